// Round 1
// 638.107 us; speedup vs baseline: 1.0112x; 1.0112x over previous
//
#include <hip/hip_runtime.h>

typedef _Float16 f16;
typedef f16 f16x2 __attribute__((ext_vector_type(2)));
typedef f16 f16x4 __attribute__((ext_vector_type(4)));
typedef f16 f16x8 __attribute__((ext_vector_type(8)));
typedef float floatx4 __attribute__((ext_vector_type(4)));

#define LDS_AS(p) ((__attribute__((address_space(3))) unsigned int*)(p))
#define GLB_AS(p) ((const __attribute__((address_space(1))) unsigned int*)(p))

__device__ __forceinline__ void gload16(const void* g, void* l) {
  __builtin_amdgcn_global_load_lds(GLB_AS(g), LDS_AS(l), 16, 0, 0);
}

// ---------------------------------------------------------------------------
// Kernel 1: blocks 0..255 convert proj_w fp32 -> fp16 (512*512 elements).
//           blocks 256..287 build the bias table biasT[h][m][fr][nt] =
//           rpb[rel_index[m*64 + nt*16+fr]*8 + h]  (8*64*16*4 = 32768 f32),
//           so the attention softmax reads bias as ONE coalesced dwordx4
//           instead of 2-level scalar gathers.
// ---------------------------------------------------------------------------
__global__ __launch_bounds__(256) void wconv_kernel(
    const float* __restrict__ w, f16* __restrict__ wh,
    const float* __restrict__ rpb, const int* __restrict__ rel_index,
    float* __restrict__ biasT) {
  if (blockIdx.x < 256) {
    const int i = (blockIdx.x * 256 + threadIdx.x) * 4;
    const float4 v = *(const float4*)(w + i);
    f16x4 o;
    o.x = (f16)v.x; o.y = (f16)v.y; o.z = (f16)v.z; o.w = (f16)v.w;
    *(f16x4*)(wh + i) = o;
  } else {
    const int o  = (blockIdx.x - 256) * 256 + threadIdx.x;  // 0..8191
    const int fr = o & 15;
    const int m  = (o >> 4) & 63;
    const int h  = o >> 10;
#pragma unroll
    for (int nt = 0; nt < 4; nt++)
      biasT[o * 4 + nt] = rpb[rel_index[m * 64 + nt * 16 + fr] * 8 + h];
  }
}

// ---------------------------------------------------------------------------
// Kernel 2: windowed cosine attention. One block = one (window, head).
// grid = 8192 blocks, 256 threads (4 waves).
// Phase 1a: 4ch x 4tok per thread -> f16x4 (b64) LDS stores (12 vector
//           writes/thread vs 48 scalar before).
// Phase 1b: LDS-local L2-normalization of q,k (unchanged).
// Phase 2:  MFMA QK^T; softmax bias from precomputed table (1 dwordx4/row).
// Phase 3:  MFMA PV; O staged into ps (aliases qs) then cooperative f16x8
//           stores -> 64B-granule coalesced X writes.
// ps aliases qs: each wave reads/writes ONLY rows [m0, m0+16) of both.
// ---------------------------------------------------------------------------
__global__ __launch_bounds__(256) void attn_kernel(
    const float* __restrict__ qkv, const float* __restrict__ logit_scale,
    const float* __restrict__ biasT, f16* __restrict__ X) {
  __shared__ f16 qs[64 * 72];   // [token][channel] stride 72; reused as ps
  __shared__ f16 ks[64 * 72];   // [token][channel]
  __shared__ f16 vs[64 * 72];   // [channel][token] (transposed for PV B-frag)
  f16* const ps = qs;           // safe: per-wave-exclusive rows in both roles

  const int bid = blockIdx.x;
  const int h   = bid & 7;
  const int win = bid >> 3;
  const int wx  = win & 15;
  const int wy  = (win >> 4) & 15;
  const int b   = win >> 8;

  const int tid  = threadIdx.x;
  const int wave = tid >> 6;
  const int lane = tid & 63;

  // ---- phase 1a: thread = (4 channels c0..c0+3, 4 tokens t0..t0+3)
  {
    const int c0 = (tid >> 4) * 4;       // 0..60
    const int tq = tid & 15;
    const int t0 = tq * 4;               // 0..60, same window row
    const int ty = t0 >> 3;
    const int xh = (t0 >> 2) & 1;
    const size_t base = (size_t)((b * 8 + h) * 192) * 16384 +
                        (size_t)(wy * 8 + ty) * 128 + wx * 8 + xh * 4;
    const float* gp = qkv + base;
    floatx4 q4[4], k4[4], v4[4];
#pragma unroll
    for (int cc = 0; cc < 4; cc++) {
      q4[cc] = *(const floatx4*)(gp + (size_t)(c0 + cc) * 16384);
      k4[cc] = *(const floatx4*)(gp + (size_t)(64 + c0 + cc) * 16384);
      v4[cc] = *(const floatx4*)(gp + (size_t)(128 + c0 + cc) * 16384);
    }
#pragma unroll
    for (int j = 0; j < 4; j++) {        // token-major: pack across channels
      f16x4 qh, kh;
      qh.x = (f16)q4[0][j]; qh.y = (f16)q4[1][j];
      qh.z = (f16)q4[2][j]; qh.w = (f16)q4[3][j];
      kh.x = (f16)k4[0][j]; kh.y = (f16)k4[1][j];
      kh.z = (f16)k4[2][j]; kh.w = (f16)k4[3][j];
      *(f16x4*)(qs + (t0 + j) * 72 + c0) = qh;
      *(f16x4*)(ks + (t0 + j) * 72 + c0) = kh;
    }
#pragma unroll
    for (int cc = 0; cc < 4; cc++) {     // V transposed: contiguous tokens
      f16x4 vh;
      vh.x = (f16)v4[cc][0]; vh.y = (f16)v4[cc][1];
      vh.z = (f16)v4[cc][2]; vh.w = (f16)v4[cc][3];
      *(f16x4*)(vs + (c0 + cc) * 72 + t0) = vh;
    }
  }
  __syncthreads();

  // ---- phase 1b: L2-normalize q (tid<128) and k (tid>=128) in place
  {
    const int token = (tid & 127) >> 1;
    const int half  = tid & 1;
    f16* rowp = ((tid < 128) ? qs : ks) + token * 72 + half * 32;
    f16x8 d[4];
    float ssq = 0.f;
#pragma unroll
    for (int i = 0; i < 4; i++) {
      d[i] = *(const f16x8*)(rowp + i * 8);
#pragma unroll
      for (int e = 0; e < 8; e++) {
        const float f = (float)d[i][e];
        ssq += f * f;
      }
    }
    ssq += __shfl_xor(ssq, 1);   // pairs (2t,2t+1) stay within a wave
    const float rs = 1.0f / fmaxf(sqrtf(ssq), 1e-12f);
#pragma unroll
    for (int i = 0; i < 4; i++) {
#pragma unroll
      for (int e = 0; e < 8; e++) d[i][e] = (f16)((float)d[i][e] * rs);
      *(f16x8*)(rowp + i * 8) = d[i];
    }
  }
  __syncthreads();

  // ---- phase 2: S = scale*(Q K^T) + bias; row softmax; -> ps (f16)
  const int fr = lane & 15;
  const int g  = lane >> 4;
  const int m0 = wave * 16;
  const float scale = __expf(fminf(logit_scale[h], 4.60517019f));  // ln(100)
  const float* biasH = biasT + h * 4096;

  floatx4 acc[4];
  {
    const f16x8 a0 = *(const f16x8*)(qs + (m0 + fr) * 72 + g * 8);
    const f16x8 a1 = *(const f16x8*)(qs + (m0 + fr) * 72 + 32 + g * 8);
#pragma unroll
    for (int nt = 0; nt < 4; nt++) {
      const f16x8 b0 = *(const f16x8*)(ks + (nt * 16 + fr) * 72 + g * 8);
      const f16x8 b1 = *(const f16x8*)(ks + (nt * 16 + fr) * 72 + 32 + g * 8);
      floatx4 z = {0.f, 0.f, 0.f, 0.f};
      z = __builtin_amdgcn_mfma_f32_16x16x32_f16(a0, b0, z, 0, 0, 0);
      z = __builtin_amdgcn_mfma_f32_16x16x32_f16(a1, b1, z, 0, 0, 0);
      acc[nt] = z;
    }
  }

#pragma unroll
  for (int r = 0; r < 4; r++) {
    const int m = m0 + g * 4 + r;   // C-layout row
    const floatx4 bv = *(const floatx4*)(biasH + m * 64 + fr * 4);
    float v0[4];
    float mx = -1e30f;
#pragma unroll
    for (int nt = 0; nt < 4; nt++) {
      const float val = acc[nt][r] * scale + bv[nt];
      v0[nt] = val;
      mx = fmaxf(mx, val);
    }
    mx = fmaxf(mx, __shfl_xor(mx, 1));
    mx = fmaxf(mx, __shfl_xor(mx, 2));
    mx = fmaxf(mx, __shfl_xor(mx, 4));
    mx = fmaxf(mx, __shfl_xor(mx, 8));
    float s = 0.f;
#pragma unroll
    for (int nt = 0; nt < 4; nt++) {
      v0[nt] = __expf(v0[nt] - mx);
      s += v0[nt];
    }
    s += __shfl_xor(s, 1);
    s += __shfl_xor(s, 2);
    s += __shfl_xor(s, 4);
    s += __shfl_xor(s, 8);
    const float rinv = 1.0f / s;
#pragma unroll
    for (int nt = 0; nt < 4; nt++)
      ps[m * 72 + nt * 16 + fr] = (f16)(v0[nt] * rinv);
  }

  // ---- phase 3: O = P V (ps rows m0..m0+15 written by THIS wave only)
  floatx4 oacc[4];
  {
    const f16x8 pa0 = *(const f16x8*)(ps + (m0 + fr) * 72 + g * 8);
    const f16x8 pa1 = *(const f16x8*)(ps + (m0 + fr) * 72 + 32 + g * 8);
#pragma unroll
    for (int dt = 0; dt < 4; dt++) {
      const f16x8 vb0 = *(const f16x8*)(vs + (dt * 16 + fr) * 72 + g * 8);
      const f16x8 vb1 = *(const f16x8*)(vs + (dt * 16 + fr) * 72 + 32 + g * 8);
      floatx4 z = {0.f, 0.f, 0.f, 0.f};
      z = __builtin_amdgcn_mfma_f32_16x16x32_f16(pa0, vb0, z, 0, 0, 0);
      z = __builtin_amdgcn_mfma_f32_16x16x32_f16(pa1, vb1, z, 0, 0, 0);
      oacc[dt] = z;
    }
  }

  // stage O into ps ([token][channel]) -- own rows only, no barrier needed
#pragma unroll
  for (int r = 0; r < 4; r++) {
    const int m = m0 + g * 4 + r;
#pragma unroll
    for (int dt = 0; dt < 4; dt++)
      ps[m * 72 + dt * 16 + fr] = (f16)oacc[dt][r];
  }
  __syncthreads();

  // cooperative coalesced X write: thread = (token, 16-channel slice)
  {
    const int t  = tid >> 2;           // 0..63
    const int ci = (tid & 3) * 16;     // 0,16,32,48
    const int ty = t >> 3, tx = t & 7;
    const size_t npix = (size_t)(b * 128 + wy * 8 + ty) * 128 + wx * 8 + tx;
    f16* xp = X + npix * 512 + h * 64 + ci;
    *(f16x8*)(xp)     = *(const f16x8*)(ps + t * 72 + ci);
    *(f16x8*)(xp + 8) = *(const f16x8*)(ps + t * 72 + ci + 8);
  }
}

// ---------------------------------------------------------------------------
// Kernel 3: projection GEMM. out[o][pix] = sum_c W[o][c] * X[pix][c] + b[o].
// M=512, N=65536, K=512. 128x128 tiles, BK=64 (8 iters, barriers halved).
// XOR-swizzled LDS chunk layout (applied to the GLOBAL source index, so the
// lane-linear global_load_lds destination is preserved): chunk c8 of row r
// lives at slot c8^(r&7). Frag-read banks: ((kk*4+g)^(fr&7))*4 -> all 32
// banks, 2-way aliasing = free (was 8-way conflicted at BK=32 unswizzled).
// ---------------------------------------------------------------------------
__global__ __launch_bounds__(256) void proj_kernel(
    const f16* __restrict__ Wh, const f16* __restrict__ X,
    const float* __restrict__ bias, float* __restrict__ out) {
  __shared__ f16 As[128 * 64];  // W tile [o-local][c-local], swizzled
  __shared__ f16 Bs[128 * 64];  // X tile [pix-local][c-local], swizzled

  const int tid  = threadIdx.x;
  const int lane = tid & 63;
  const int wave = tid >> 6;
  const int o0 = (blockIdx.x & 3) * 128;
  const int p0 = (blockIdx.x >> 2) * 128;

  const int fr = lane & 15, g = lane >> 4;
  const int wr = wave >> 1, wc = wave & 1;

  floatx4 acc[4][4] = {};

  // staging: chunk j covers slot = j*256 + tid; row = slot>>3; stored chunk
  // c8 = (tid&7) ^ (row&7). 8 consecutive lanes read one row's 8 chunks
  // permuted -> still one 128B coalesced region.
  const f16* gA[4];
  const f16* gB[4];
#pragma unroll
  for (int j = 0; j < 4; j++) {
    const int slot = j * 256 + tid;
    const int row  = slot >> 3;
    const int c8   = (tid & 7) ^ (row & 7);
    gA[j] = Wh + (size_t)(o0 + row) * 512 + c8 * 8;
    gB[j] = X  + (size_t)(p0 + row) * 512 + c8 * 8;
  }

  for (int kc = 0; kc < 512; kc += 64) {
#pragma unroll
    for (int j = 0; j < 4; j++) {
      gload16(gA[j] + kc, As + (j * 256 + tid) * 8);
      gload16(gB[j] + kc, Bs + (j * 256 + tid) * 8);
    }
    __syncthreads();   // drains vmcnt -> LDS tiles ready
#pragma unroll
    for (int kk = 0; kk < 2; kk++) {
      f16x8 af[4], bfr[4];
#pragma unroll
      for (int mt = 0; mt < 4; mt++) {
        const int row = wr * 64 + mt * 16 + fr;
        af[mt] = *(const f16x8*)(As + row * 64 + (((kk * 4 + g) ^ (row & 7)) * 8));
      }
#pragma unroll
      for (int nt = 0; nt < 4; nt++) {
        const int row = wc * 64 + nt * 16 + fr;
        bfr[nt] = *(const f16x8*)(Bs + row * 64 + (((kk * 4 + g) ^ (row & 7)) * 8));
      }
#pragma unroll
      for (int mt = 0; mt < 4; mt++)
#pragma unroll
        for (int nt = 0; nt < 4; nt++)
          acc[mt][nt] = __builtin_amdgcn_mfma_f32_16x16x32_f16(af[mt], bfr[nt],
                                                               acc[mt][nt], 0, 0, 0);
    }
    __syncthreads();   // protect LDS before next-iter overwrite
  }

  // epilogue: pix tile p0..p0+127 lies in one (b, y) row -> coalesced stores
  const int bidx = p0 >> 14;
  const int rem0 = p0 & 16383;
#pragma unroll
  for (int mt = 0; mt < 4; mt++) {
#pragma unroll
    for (int r = 0; r < 4; r++) {
      const int o = o0 + wr * 64 + mt * 16 + g * 4 + r;
      const float bv = bias[o];
      float* op = out + ((size_t)(bidx * 512 + o) << 14) + rem0 + wc * 64;
#pragma unroll
      for (int nt = 0; nt < 4; nt++) op[nt * 16 + fr] = acc[mt][nt][r] + bv;
    }
  }
}

// ---------------------------------------------------------------------------
extern "C" void kernel_launch(void* const* d_in, const int* in_sizes, int n_in,
                              void* d_out, int out_size, void* d_ws, size_t ws_size,
                              hipStream_t stream) {
  const float* qkv         = (const float*)d_in[0];
  const float* logit_scale = (const float*)d_in[1];
  const float* rpb         = (const float*)d_in[2];
  const float* proj_w      = (const float*)d_in[3];
  const float* proj_b      = (const float*)d_in[4];
  const int*   rel_index   = (const int*)d_in[5];
  float* out = (float*)d_out;

  f16*   Wh    = (f16*)d_ws;                                  // 512 KiB
  f16*   X     = (f16*)((char*)d_ws + (512 * 512 * 2));       // 64 MiB
  float* biasT = (float*)((char*)d_ws + (512 * 512 * 2) + (65536 * 512 * 2)); // 128 KiB

  hipLaunchKernelGGL(wconv_kernel, dim3(288), dim3(256), 0, stream,
                     proj_w, Wh, rpb, rel_index, biasT);
  hipLaunchKernelGGL(attn_kernel, dim3(8192), dim3(256), 0, stream,
                     qkv, logit_scale, biasT, X);
  hipLaunchKernelGGL(proj_kernel, dim3(2048), dim3(256), 0, stream,
                     Wh, X, proj_b, out);
}